// Round 4
// baseline (221.812 us; speedup 1.0000x reference)
//
#include <hip/hip_runtime.h>

typedef __bf16 bf16;
typedef __bf16 bf16x4 __attribute__((ext_vector_type(4)));
typedef __bf16 bf16x8 __attribute__((ext_vector_type(8)));
typedef float f32x4 __attribute__((ext_vector_type(4)));

#define MFMA16(a,b,c) __builtin_amdgcn_mfma_f32_16x16x32_bf16((a),(b),(c),0,0,0)

__device__ __forceinline__ float silu_f(float y){ return y/(1.f+__expf(-y)); }

// load 8 consecutive floats, convert to bf16x8 fragment
__device__ __forceinline__ bf16x8 ld8f(const float* __restrict__ p){
    float4 a = *(const float4*)p;
    float4 b = *(const float4*)(p+4);
    bf16x8 r;
    r[0]=(bf16)a.x; r[1]=(bf16)a.y; r[2]=(bf16)a.z; r[3]=(bf16)a.w;
    r[4]=(bf16)b.x; r[5]=(bf16)b.y; r[6]=(bf16)b.z; r[7]=(bf16)b.w;
    return r;
}

#define BN_SCALE 0.9999950000374997f   // 1/sqrt(1+1e-5)

// ---------------------------------------------------------------------------
// Kernel A: fused 1x1 conv + BN + SiLU for theta(Q), phi(K), g(V).
// x: [8][256][3136] fp32.  Outputs (bf16): Q,K [b][3136][32] pos-major,
// Vt [b][128][3136] channel-major (via swapped mfma operands).
// ---------------------------------------------------------------------------
__global__ __launch_bounds__(256) void qkv_kernel(
    const float* __restrict__ xg,
    const float* __restrict__ wth, const float* __restrict__ gth, const float* __restrict__ bth,
    const float* __restrict__ wph, const float* __restrict__ gph, const float* __restrict__ bph,
    const float* __restrict__ wgg, const float* __restrict__ ggg, const float* __restrict__ bgg,
    bf16* __restrict__ Qb, bf16* __restrict__ Kb, bf16* __restrict__ Vtb)
{
    const int b = blockIdx.x, pt = blockIdx.y;
    const int p0 = pt*64;
    const int t = threadIdx.x;
    const int lane = t & 63, wv = t >> 6;
    const int lc = lane & 15, lg = lane >> 4;

    __shared__ __align__(16) bf16 xT[64][264];   // [pos][c]

    {
        const int cbase = t >> 4;        // 0..15
        const int p4 = (t & 15) * 4;     // 0..60
        #pragma unroll
        for (int r = 0; r < 16; ++r) {
            int c = r*16 + cbase;
            float4 v = *(const float4*)(xg + ((size_t)(b*256 + c))*3136 + p0 + p4);
            xT[p4+0][c] = (bf16)v.x; xT[p4+1][c] = (bf16)v.y;
            xT[p4+2][c] = (bf16)v.z; xT[p4+3][c] = (bf16)v.w;
        }
    }
    __syncthreads();

    const f32x4 fz = {0.f,0.f,0.f,0.f};

    for (int tt = 0; tt < 3; ++tt) {
        const int ot = wv*3 + tt;        // 0,1=Q 2,3=K 4..11=V
        if (ot < 4) {
            const float *W, *gam, *bet; bf16* dst; int ol;
            if (ot < 2) { W=wth; gam=gth; bet=bth; dst=Qb; ol=ot*16; }
            else        { W=wph; gam=gph; bet=bph; dst=Kb; ol=(ot-2)*16; }
            f32x4 acc[4]; acc[0]=fz; acc[1]=fz; acc[2]=fz; acc[3]=fz;
            #pragma unroll
            for (int ks = 0; ks < 8; ++ks) {
                bf16x8 wf = ld8f(W + (size_t)(ol+lc)*256 + ks*32 + lg*8);
                #pragma unroll
                for (int pf = 0; pf < 4; ++pf) {
                    bf16x8 af = *(const bf16x8*)&xT[pf*16+lc][ks*32+lg*8];
                    acc[pf] = MFMA16(af, wf, acc[pf]);
                }
            }
            const int oc = ol + lc;
            const float sc = gam[oc] * BN_SCALE;
            const float bi = bet[oc];
            #pragma unroll
            for (int pf = 0; pf < 4; ++pf)
                #pragma unroll
                for (int r = 0; r < 4; ++r) {
                    int pos = p0 + pf*16 + lg*4 + r;
                    dst[((size_t)b*3136 + pos)*32 + oc] = (bf16)silu_f(acc[pf][r]*sc + bi);
                }
        } else {
            const int ol = (ot-4)*16;
            f32x4 acc[4]; acc[0]=fz; acc[1]=fz; acc[2]=fz; acc[3]=fz;
            #pragma unroll
            for (int ks = 0; ks < 8; ++ks) {
                bf16x8 wf = ld8f(wgg + (size_t)(ol+lc)*256 + ks*32 + lg*8);
                #pragma unroll
                for (int pc = 0; pc < 4; ++pc) {
                    bf16x8 xf = *(const bf16x8*)&xT[pc*16+lc][ks*32+lg*8];
                    acc[pc] = MFMA16(wf, xf, acc[pc]);
                }
            }
            #pragma unroll
            for (int r = 0; r < 4; ++r) {
                const int oc = ol + lg*4 + r;
                const float sc = ggg[oc] * BN_SCALE;
                const float bi = bgg[oc];
                #pragma unroll
                for (int pc = 0; pc < 4; ++pc) {
                    int pos = p0 + pc*16 + lc;
                    Vtb[((size_t)b*128 + oc)*3136 + pos] = (bf16)silu_f(acc[pc][r]*sc + bi);
                }
            }
        }
    }
}

// ---------------------------------------------------------------------------
// Kernel B: flash attention, split-K x4, T14 reg-staged prefetch, T2 V-swizzle.
// Block = 64 q-rows (4 waves x 16). defer-max rescale (THR=8).
// Vlds: linear [128][64] bf16 (128B rows), byte ^= (row&7)<<4 both sides.
// ---------------------------------------------------------------------------
__global__ __launch_bounds__(256) void attn_kernel(
    const bf16* __restrict__ Qb, const bf16* __restrict__ Kb,
    const bf16* __restrict__ Vtb, bf16* __restrict__ Opart,
    float* __restrict__ mpart, float* __restrict__ lpart)
{
    const int b = blockIdx.x, qt = blockIdx.y, z = blockIdx.z;
    const int kt0 = (z==0) ? 0  : 13 + 12*(z-1);
    const int kt1 = (z==3) ? 49 : 13 + 12*z;
    const int p0 = qt*64;
    const int t = threadIdx.x;
    const int lane = t & 63, wv = t >> 6;
    const int lc = lane & 15, lg = lane >> 4;

    __shared__ __align__(16) bf16 Klds[64][40];
    __shared__ __align__(16) bf16 Vlds[128*64];      // swizzled, 128B rows
    __shared__ __align__(16) bf16 Plds[4][16*72];

    const bf16* Kbase = Kb + (size_t)b*3136*32;
    const bf16* Vbase = Vtb + (size_t)b*128*3136;

    bf16x8 qf = *(const bf16x8*)(Qb + ((size_t)b*3136 + p0 + wv*16 + lc)*32 + lg*8);

    float mrow[4] = {-1e30f,-1e30f,-1e30f,-1e30f};
    float lrow[4] = {0.f,0.f,0.f,0.f};
    const f32x4 fz = {0.f,0.f,0.f,0.f};
    f32x4 oacc[8];
    #pragma unroll
    for (int cf = 0; cf < 8; ++cf) oacc[cf] = fz;

    const int krow = t >> 2, kkp = (t & 3) * 8;
    const int vrow0 = t >> 3;          // w*8 + (lane>>3): 8 rows per wave per pass
    const int vj    = t & 7;           // 16B chunk within 128B row
    const int pxorw = (lg >> 1) << 4;
    const int pxorr = (lc >> 3) << 4;

    // T14 prologue: prefetch first tile into registers
    bf16x8 kreg; bf16x8 vreg0, vreg1, vreg2, vreg3;
    {
        const int k0 = kt0*64;
        kreg  = *(const bf16x8*)(Kbase + (size_t)(k0+krow)*32 + kkp);
        vreg0 = *(const bf16x8*)(Vbase + (size_t)(0*32+vrow0)*3136 + k0 + vj*8);
        vreg1 = *(const bf16x8*)(Vbase + (size_t)(1*32+vrow0)*3136 + k0 + vj*8);
        vreg2 = *(const bf16x8*)(Vbase + (size_t)(2*32+vrow0)*3136 + k0 + vj*8);
        vreg3 = *(const bf16x8*)(Vbase + (size_t)(3*32+vrow0)*3136 + k0 + vj*8);
    }
    const int vxor = (vrow0 & 7) << 4;

    for (int kt = kt0; kt < kt1; ++kt) {
        __syncthreads();   // previous tile fully consumed
        // write staged regs -> LDS
        *(bf16x8*)&Klds[krow][kkp] = kreg;
        *(bf16x8*)((char*)Vlds + (0*32+vrow0)*128 + ((vj*16) ^ vxor)) = vreg0;
        *(bf16x8*)((char*)Vlds + (1*32+vrow0)*128 + ((vj*16) ^ vxor)) = vreg1;
        *(bf16x8*)((char*)Vlds + (2*32+vrow0)*128 + ((vj*16) ^ vxor)) = vreg2;
        *(bf16x8*)((char*)Vlds + (3*32+vrow0)*128 + ((vj*16) ^ vxor)) = vreg3;
        __syncthreads();

        // T14: issue next tile's global loads (latency hides under compute)
        if (kt+1 < kt1) {
            const int kn = (kt+1)*64;
            kreg  = *(const bf16x8*)(Kbase + (size_t)(kn+krow)*32 + kkp);
            vreg0 = *(const bf16x8*)(Vbase + (size_t)(0*32+vrow0)*3136 + kn + vj*8);
            vreg1 = *(const bf16x8*)(Vbase + (size_t)(1*32+vrow0)*3136 + kn + vj*8);
            vreg2 = *(const bf16x8*)(Vbase + (size_t)(2*32+vrow0)*3136 + kn + vj*8);
            vreg3 = *(const bf16x8*)(Vbase + (size_t)(3*32+vrow0)*3136 + kn + vj*8);
        }

        // S tile: D col=key(lc), row=q(lg*4+r)
        f32x4 s[4];
        #pragma unroll
        for (int nf = 0; nf < 4; ++nf) {
            bf16x8 kf = *(const bf16x8*)&Klds[nf*16+lc][lg*8];
            s[nf] = MFMA16(qf, kf, fz);
        }

        // tile max per row (reduce across 16 key-lanes)
        float mx[4];
        #pragma unroll
        for (int r = 0; r < 4; ++r) {
            float m = fmaxf(fmaxf(s[0][r], s[1][r]), fmaxf(s[2][r], s[3][r]));
            #pragma unroll
            for (int d = 1; d < 16; d <<= 1) m = fmaxf(m, __shfl_xor(m, d));
            mx[r] = m;
        }
        // defer-max: only rescale when some row grew by > 8
        bool ok = (mx[0] <= mrow[0]+8.f) && (mx[1] <= mrow[1]+8.f)
               && (mx[2] <= mrow[2]+8.f) && (mx[3] <= mrow[3]+8.f);
        if (!__all(ok)) {
            float scale[4];
            #pragma unroll
            for (int r = 0; r < 4; ++r) {
                float nm = fmaxf(mrow[r], mx[r]);
                scale[r] = __expf(mrow[r] - nm);
                mrow[r] = nm;
                lrow[r] *= scale[r];
            }
            #pragma unroll
            for (int cf = 0; cf < 8; ++cf)
                #pragma unroll
                for (int r = 0; r < 4; ++r) oacc[cf][r] *= scale[r];
        }
        // exp + row sums with current mrow
        #pragma unroll
        for (int r = 0; r < 4; ++r) {
            float ps = 0.f;
            #pragma unroll
            for (int nf = 0; nf < 4; ++nf) {
                float pv = __expf(s[nf][r] - mrow[r]); s[nf][r] = pv; ps += pv;
            }
            #pragma unroll
            for (int d = 1; d < 16; d <<= 1) ps += __shfl_xor(ps, d);
            lrow[r] += ps;
        }

        // P -> per-wave LDS (swizzled columns)
        #pragma unroll
        for (int nf = 0; nf < 4; ++nf)
            #pragma unroll
            for (int r = 0; r < 4; ++r)
                Plds[wv][(lg*4+r)*72 + ((nf*16+lc) ^ pxorw)] = (bf16)s[nf][r];

        // O += P @ V
        __builtin_amdgcn_s_setprio(1);
        #pragma unroll
        for (int ks = 0; ks < 2; ++ks) {
            bf16x8 pfr = *(const bf16x8*)&Plds[wv][lc*72 + ((ks*32 + lg*8) ^ pxorr)];
            #pragma unroll
            for (int cf = 0; cf < 8; ++cf) {
                const int vrow = cf*16 + lc;
                bf16x8 vf = *(const bf16x8*)((char*)Vlds + vrow*128
                                 + ((ks*64 + lg*16) ^ ((vrow & 7) << 4)));
                oacc[cf] = MFMA16(pfr, vf, oacc[cf]);
            }
        }
        __builtin_amdgcn_s_setprio(0);
    }

    // store unnormalized partial + m,l
    #pragma unroll
    for (int cf = 0; cf < 8; ++cf)
        #pragma unroll
        for (int r = 0; r < 4; ++r) {
            int q = p0 + wv*16 + lg*4 + r;
            Opart[((size_t)(z*8+b)*3136 + q)*128 + cf*16 + lc] = (bf16)oacc[cf][r];
        }
    if (lc == 0) {
        #pragma unroll
        for (int r = 0; r < 4; ++r) {
            int q = p0 + wv*16 + lg*4 + r;
            size_t idx = (size_t)(z*8+b)*3136 + q;
            mpart[idx] = mrow[r];
            lpart[idx] = lrow[r];
        }
    }
}

// ---------------------------------------------------------------------------
// Kernel C: combine 4 split partials inline, then 1x1 conv (128->256)
// + BN + SiLU + residual (fp32 x).
// ---------------------------------------------------------------------------
__global__ __launch_bounds__(256) void out_kernel(
    const bf16* __restrict__ Opart, const float* __restrict__ mpart,
    const float* __restrict__ lpart, const float* __restrict__ wout,
    const float* __restrict__ gout, const float* __restrict__ bout,
    const float* __restrict__ xg, float* __restrict__ outp)
{
    const int b = blockIdx.x, pt = blockIdx.y;
    const int p0 = pt*64;
    const int t = threadIdx.x;
    const int lane = t & 63, wv = t >> 6;
    const int lc = lane & 15, lg = lane >> 4;

    __shared__ __align__(16) bf16 Olds[64][136];
    __shared__ __align__(16) bf16 outlds[4][64][72];

    // stage: combine split partials -> normalized O tile in LDS
    {
        const int row = t >> 2;          // 0..63
        const int cb = (t & 3) * 32;     // bf16 col base
        const int q = p0 + row;
        float m0 = mpart[(size_t)(0*8+b)*3136 + q];
        float m1 = mpart[(size_t)(1*8+b)*3136 + q];
        float m2 = mpart[(size_t)(2*8+b)*3136 + q];
        float m3 = mpart[(size_t)(3*8+b)*3136 + q];
        float M = fmaxf(fmaxf(m0,m1), fmaxf(m2,m3));
        float w0 = __expf(m0-M), w1 = __expf(m1-M), w2 = __expf(m2-M), w3 = __expf(m3-M);
        float L = lpart[(size_t)(0*8+b)*3136 + q]*w0 + lpart[(size_t)(1*8+b)*3136 + q]*w1
                + lpart[(size_t)(2*8+b)*3136 + q]*w2 + lpart[(size_t)(3*8+b)*3136 + q]*w3;
        float inv = 1.f / L;
        w0 *= inv; w1 *= inv; w2 *= inv; w3 *= inv;
        #pragma unroll
        for (int r = 0; r < 4; ++r) {
            int c8 = cb + r*8;
            float o[8];
            #pragma unroll
            for (int j = 0; j < 8; ++j) o[j] = 0.f;
            bf16x8 v0 = *(const bf16x8*)(Opart + ((size_t)(0*8+b)*3136 + q)*128 + c8);
            bf16x8 v1 = *(const bf16x8*)(Opart + ((size_t)(1*8+b)*3136 + q)*128 + c8);
            bf16x8 v2 = *(const bf16x8*)(Opart + ((size_t)(2*8+b)*3136 + q)*128 + c8);
            bf16x8 v3 = *(const bf16x8*)(Opart + ((size_t)(3*8+b)*3136 + q)*128 + c8);
            #pragma unroll
            for (int j = 0; j < 8; ++j)
                o[j] = w0*(float)v0[j] + w1*(float)v1[j] + w2*(float)v2[j] + w3*(float)v3[j];
            bf16x8 rr;
            #pragma unroll
            for (int j = 0; j < 8; ++j) rr[j] = (bf16)o[j];
            *(bf16x8*)&Olds[row][c8] = rr;
        }
    }
    __syncthreads();

    const f32x4 fz = {0.f,0.f,0.f,0.f};
    f32x4 acc[4][4];
    #pragma unroll
    for (int pf = 0; pf < 4; ++pf)
        #pragma unroll
        for (int nf = 0; nf < 4; ++nf) acc[pf][nf] = fz;

    #pragma unroll
    for (int ks = 0; ks < 4; ++ks) {
        bf16x8 wf[4];
        #pragma unroll
        for (int nf = 0; nf < 4; ++nf)
            wf[nf] = ld8f(wout + (size_t)(wv*64 + nf*16 + lc)*128 + ks*32 + lg*8);
        #pragma unroll
        for (int pf = 0; pf < 4; ++pf) {
            bf16x8 af = *(const bf16x8*)&Olds[pf*16+lc][ks*32+lg*8];
            #pragma unroll
            for (int nf = 0; nf < 4; ++nf)
                acc[pf][nf] = MFMA16(af, wf[nf], acc[pf][nf]);
        }
    }

    #pragma unroll
    for (int nf = 0; nf < 4; ++nf) {
        const int oc = wv*64 + nf*16 + lc;
        const float sc = gout[oc] * BN_SCALE;
        const float bi = bout[oc];
        #pragma unroll
        for (int pf = 0; pf < 4; ++pf)
            #pragma unroll
            for (int r = 0; r < 4; ++r)
                outlds[wv][nf*16+lc][pf*16+lg*4+r] = (bf16)silu_f(acc[pf][nf][r]*sc + bi);
    }

    #pragma unroll
    for (int i = 0; i < 16; ++i) {
        const int orow = i*4 + lg;
        const int oc = wv*64 + orow;
        const int p4 = lc*4;
        bf16x4 vo = *(const bf16x4*)&outlds[wv][orow][p4];
        float4 vx = *(const float4*)(xg + ((size_t)b*256 + oc)*3136 + p0 + p4);
        float4 res;
        res.x = (float)vo[0] + vx.x;
        res.y = (float)vo[1] + vx.y;
        res.z = (float)vo[2] + vx.z;
        res.w = (float)vo[3] + vx.w;
        *(float4*)(outp + ((size_t)b*256 + oc)*3136 + p0 + p4) = res;
    }
}

extern "C" void kernel_launch(void* const* d_in, const int* in_sizes, int n_in,
                              void* d_out, int out_size, void* d_ws, size_t ws_size,
                              hipStream_t stream)
{
    const float* x    = (const float*)d_in[0];
    const float* wth  = (const float*)d_in[1];
    const float* gth  = (const float*)d_in[2];
    const float* bth  = (const float*)d_in[3];
    const float* wph  = (const float*)d_in[4];
    const float* gph  = (const float*)d_in[5];
    const float* bph  = (const float*)d_in[6];
    const float* wgg  = (const float*)d_in[7];
    const float* ggg  = (const float*)d_in[8];
    const float* bgg  = (const float*)d_in[9];
    const float* wout = (const float*)d_in[10];
    const float* gout = (const float*)d_in[11];
    const float* bout = (const float*)d_in[12];

    bf16* ws  = (bf16*)d_ws;
    bf16* Qb    = ws;                                  // [8][3136][32]
    bf16* Kb    = Qb + (size_t)8*3136*32;              // [8][3136][32]
    bf16* Vtb   = Kb + (size_t)8*3136*32;              // [8][128][3136]
    bf16* Opart = Vtb + (size_t)8*128*3136;            // [4][8][3136][128]
    float* mpart = (float*)(Opart + (size_t)4*8*3136*128);  // [4][8][3136]
    float* lpart = mpart + (size_t)4*8*3136;                // [4][8][3136]

    dim3 blk(256);
    qkv_kernel<<<dim3(8,49), blk, 0, stream>>>(x, wth, gth, bth, wph, gph, bph,
                                               wgg, ggg, bgg, Qb, Kb, Vtb);
    attn_kernel<<<dim3(8,49,4), blk, 0, stream>>>(Qb, Kb, Vtb, Opart, mpart, lpart);
    out_kernel<<<dim3(8,49), blk, 0, stream>>>(Opart, mpart, lpart,
                                               wout, gout, bout, x, (float*)d_out);
}

// Round 5
// 214.796 us; speedup vs baseline: 1.0327x; 1.0327x over previous
//
#include <hip/hip_runtime.h>

typedef __bf16 bf16;
typedef __bf16 bf16x4 __attribute__((ext_vector_type(4)));
typedef __bf16 bf16x8 __attribute__((ext_vector_type(8)));
typedef float f32x4 __attribute__((ext_vector_type(4)));

#define MFMA16(a,b,c) __builtin_amdgcn_mfma_f32_16x16x32_bf16((a),(b),(c),0,0,0)
#define NSPLIT 7

__device__ __forceinline__ float silu_f(float y){ return y/(1.f+__expf(-y)); }

// DPP rotate-reduce within 16 lanes (VALU pipe, no LDS ops)
template<int CTRL>
__device__ __forceinline__ float ror_max(float x){
    int y = __builtin_amdgcn_update_dpp(0, __builtin_bit_cast(int,x), CTRL, 0xf, 0xf, false);
    return fmaxf(x, __builtin_bit_cast(float,y));
}
template<int CTRL>
__device__ __forceinline__ float ror_add(float x){
    int y = __builtin_amdgcn_update_dpp(0, __builtin_bit_cast(int,x), CTRL, 0xf, 0xf, false);
    return x + __builtin_bit_cast(float,y);
}
__device__ __forceinline__ float red16_max(float x){
    x = ror_max<0x128>(x); x = ror_max<0x124>(x);
    x = ror_max<0x122>(x); x = ror_max<0x121>(x); return x;
}
__device__ __forceinline__ float red16_add(float x){
    x = ror_add<0x128>(x); x = ror_add<0x124>(x);
    x = ror_add<0x122>(x); x = ror_add<0x121>(x); return x;
}

// load 8 consecutive floats, convert to bf16x8 fragment
__device__ __forceinline__ bf16x8 ld8f(const float* __restrict__ p){
    float4 a = *(const float4*)p;
    float4 b = *(const float4*)(p+4);
    bf16x8 r;
    r[0]=(bf16)a.x; r[1]=(bf16)a.y; r[2]=(bf16)a.z; r[3]=(bf16)a.w;
    r[4]=(bf16)b.x; r[5]=(bf16)b.y; r[6]=(bf16)b.z; r[7]=(bf16)b.w;
    return r;
}

#define BN_SCALE 0.9999950000374997f   // 1/sqrt(1+1e-5)

// ---------------------------------------------------------------------------
// Kernel A: fused 1x1 conv + BN + SiLU for theta(Q), phi(K), g(V).
// pos-tile 32 (784 blocks). Staging: in-thread 4x4 transpose, b64 LDS writes.
// Outputs (bf16): Q,K [b][3136][32] pos-major, Vt [b][128][3136] c-major.
// ---------------------------------------------------------------------------
__global__ __launch_bounds__(256) void qkv_kernel(
    const float* __restrict__ xg,
    const float* __restrict__ wth, const float* __restrict__ gth, const float* __restrict__ bth,
    const float* __restrict__ wph, const float* __restrict__ gph, const float* __restrict__ bph,
    const float* __restrict__ wgg, const float* __restrict__ ggg, const float* __restrict__ bgg,
    bf16* __restrict__ Qb, bf16* __restrict__ Kb, bf16* __restrict__ Vtb)
{
    const int b = blockIdx.x, pt = blockIdx.y;
    const int p0 = pt*32;
    const int t = threadIdx.x;
    const int lane = t & 63, wv = t >> 6;
    const int lc = lane & 15, lg = lane >> 4;

    __shared__ __align__(16) bf16 xT[32][264];   // [pos][c], 528B rows (16B-aligned)

    // stage: thread loads 4 float4 from 4 channels, same 4 positions;
    // in-thread transpose -> 4 x b64 writes (conflict-free).
    {
        const int ci = t & 15;          // c-quad group
        const int pj = (t >> 4) & 7;    // pos-quad
        const int ch = t >> 7;          // 0/1
        const int p4 = pj*4;
        #pragma unroll
        for (int r = 0; r < 2; ++r) {
            const int c0 = (r*2 + ch)*64 + ci*4;
            float va[4][4];
            #pragma unroll
            for (int k = 0; k < 4; ++k) {
                float4 v = *(const float4*)(xg + ((size_t)(b*256 + c0 + k))*3136 + p0 + p4);
                va[k][0]=v.x; va[k][1]=v.y; va[k][2]=v.z; va[k][3]=v.w;
            }
            #pragma unroll
            for (int i = 0; i < 4; ++i) {
                bf16x4 w;
                w[0]=(bf16)va[0][i]; w[1]=(bf16)va[1][i];
                w[2]=(bf16)va[2][i]; w[3]=(bf16)va[3][i];
                *(bf16x4*)&xT[p4+i][c0] = w;
            }
        }
    }
    __syncthreads();

    const f32x4 fz = {0.f,0.f,0.f,0.f};

    for (int tt = 0; tt < 3; ++tt) {
        const int ot = wv*3 + tt;        // 0,1=Q 2,3=K 4..11=V
        if (ot < 4) {
            const float *W, *gam, *bet; bf16* dst; int ol;
            if (ot < 2) { W=wth; gam=gth; bet=bth; dst=Qb; ol=ot*16; }
            else        { W=wph; gam=gph; bet=bph; dst=Kb; ol=(ot-2)*16; }
            f32x4 acc[2]; acc[0]=fz; acc[1]=fz;
            #pragma unroll
            for (int ks = 0; ks < 8; ++ks) {
                bf16x8 wf = ld8f(W + (size_t)(ol+lc)*256 + ks*32 + lg*8);
                #pragma unroll
                for (int pf = 0; pf < 2; ++pf) {
                    bf16x8 af = *(const bf16x8*)&xT[pf*16+lc][ks*32+lg*8];
                    acc[pf] = MFMA16(af, wf, acc[pf]);
                }
            }
            const int oc = ol + lc;
            const float sc = gam[oc] * BN_SCALE;
            const float bi = bet[oc];
            #pragma unroll
            for (int pf = 0; pf < 2; ++pf)
                #pragma unroll
                for (int r = 0; r < 4; ++r) {
                    int pos = p0 + pf*16 + lg*4 + r;
                    dst[((size_t)b*3136 + pos)*32 + oc] = (bf16)silu_f(acc[pf][r]*sc + bi);
                }
        } else {
            const int ol = (ot-4)*16;
            f32x4 acc[2]; acc[0]=fz; acc[1]=fz;
            #pragma unroll
            for (int ks = 0; ks < 8; ++ks) {
                bf16x8 wf = ld8f(wgg + (size_t)(ol+lc)*256 + ks*32 + lg*8);
                #pragma unroll
                for (int pc = 0; pc < 2; ++pc) {
                    bf16x8 xf = *(const bf16x8*)&xT[pc*16+lc][ks*32+lg*8];
                    acc[pc] = MFMA16(wf, xf, acc[pc]);
                }
            }
            #pragma unroll
            for (int r = 0; r < 4; ++r) {
                const int oc = ol + lg*4 + r;
                const float sc = ggg[oc] * BN_SCALE;
                const float bi = bgg[oc];
                #pragma unroll
                for (int pc = 0; pc < 2; ++pc) {
                    int pos = p0 + pc*16 + lc;
                    Vtb[((size_t)b*128 + oc)*3136 + pos] = (bf16)silu_f(acc[pc][r]*sc + bi);
                }
            }
        }
    }
}

// ---------------------------------------------------------------------------
// Kernel B: flash attention, split-K x7, double-buffered K/V (1 barrier/iter),
// DPP softmax reductions (no LDS shuffles), reg-staged prefetch, V swizzle.
// ---------------------------------------------------------------------------
__global__ __launch_bounds__(256) void attn_kernel(
    const bf16* __restrict__ Qb, const bf16* __restrict__ Kb,
    const bf16* __restrict__ Vtb, bf16* __restrict__ Opart,
    float* __restrict__ mpart, float* __restrict__ lpart)
{
    const int b = blockIdx.x, qt = blockIdx.y, z = blockIdx.z;
    const int kt0 = z*7, kt1 = kt0+7;
    const int p0 = qt*64;
    const int t = threadIdx.x;
    const int lane = t & 63, wv = t >> 6;
    const int lc = lane & 15, lg = lane >> 4;

    __shared__ __align__(16) bf16 Klds[2][64][40];
    __shared__ __align__(16) bf16 Vlds[2][128*64];   // swizzled, 128B rows
    __shared__ __align__(16) bf16 Plds[4][16*72];

    const bf16* Kbase = Kb + (size_t)b*3136*32;
    const bf16* Vbase = Vtb + (size_t)b*128*3136;

    bf16x8 qf = *(const bf16x8*)(Qb + ((size_t)b*3136 + p0 + wv*16 + lc)*32 + lg*8);

    float mrow[4] = {-1e30f,-1e30f,-1e30f,-1e30f};
    float lrow[4] = {0.f,0.f,0.f,0.f};
    const f32x4 fz = {0.f,0.f,0.f,0.f};
    f32x4 oacc[8];
    #pragma unroll
    for (int cf = 0; cf < 8; ++cf) oacc[cf] = fz;

    const int krow = t >> 2, kkp = (t & 3) * 8;
    const int vrow0 = t >> 3, vj = t & 7;
    const int vxor = (vrow0 & 7) << 4;
    const int pxorw = (lg >> 1) << 4;
    const int pxorr = (lc >> 3) << 4;

    // prologue: prefetch first tile into registers
    bf16x8 kreg, vreg0, vreg1, vreg2, vreg3;
    {
        const int k0 = kt0*64;
        kreg  = *(const bf16x8*)(Kbase + (size_t)(k0+krow)*32 + kkp);
        vreg0 = *(const bf16x8*)(Vbase + (size_t)(0*32+vrow0)*3136 + k0 + vj*8);
        vreg1 = *(const bf16x8*)(Vbase + (size_t)(1*32+vrow0)*3136 + k0 + vj*8);
        vreg2 = *(const bf16x8*)(Vbase + (size_t)(2*32+vrow0)*3136 + k0 + vj*8);
        vreg3 = *(const bf16x8*)(Vbase + (size_t)(3*32+vrow0)*3136 + k0 + vj*8);
    }

    int cur = 0;
    for (int kt = kt0; kt < kt1; ++kt) {
        // write staged regs -> LDS[cur] (other waves may still compute on cur^1)
        bf16* Kl = &Klds[cur][0][0];
        bf16* Vl = &Vlds[cur][0];
        *(bf16x8*)&Kl[krow*40 + kkp] = kreg;
        *(bf16x8*)((char*)Vl + (0*32+vrow0)*128 + ((vj*16) ^ vxor)) = vreg0;
        *(bf16x8*)((char*)Vl + (1*32+vrow0)*128 + ((vj*16) ^ vxor)) = vreg1;
        *(bf16x8*)((char*)Vl + (2*32+vrow0)*128 + ((vj*16) ^ vxor)) = vreg2;
        *(bf16x8*)((char*)Vl + (3*32+vrow0)*128 + ((vj*16) ^ vxor)) = vreg3;
        __syncthreads();

        // issue next tile's global loads (hide under compute)
        if (kt+1 < kt1) {
            const int kn = (kt+1)*64;
            kreg  = *(const bf16x8*)(Kbase + (size_t)(kn+krow)*32 + kkp);
            vreg0 = *(const bf16x8*)(Vbase + (size_t)(0*32+vrow0)*3136 + kn + vj*8);
            vreg1 = *(const bf16x8*)(Vbase + (size_t)(1*32+vrow0)*3136 + kn + vj*8);
            vreg2 = *(const bf16x8*)(Vbase + (size_t)(2*32+vrow0)*3136 + kn + vj*8);
            vreg3 = *(const bf16x8*)(Vbase + (size_t)(3*32+vrow0)*3136 + kn + vj*8);
        }

        // S tile: D col=key(lc), row=q(lg*4+r)
        f32x4 s[4];
        #pragma unroll
        for (int nf = 0; nf < 4; ++nf) {
            bf16x8 kf = *(const bf16x8*)&Kl[(nf*16+lc)*40 + lg*8];
            s[nf] = MFMA16(qf, kf, fz);
        }

        // tile max per row (in-reg + DPP 16-lane reduce)
        float mx[4];
        #pragma unroll
        for (int r = 0; r < 4; ++r) {
            float m = fmaxf(fmaxf(s[0][r], s[1][r]), fmaxf(s[2][r], s[3][r]));
            mx[r] = red16_max(m);
        }
        // defer-max: only rescale when some row grew by > 8
        bool ok = (mx[0] <= mrow[0]+8.f) && (mx[1] <= mrow[1]+8.f)
               && (mx[2] <= mrow[2]+8.f) && (mx[3] <= mrow[3]+8.f);
        if (!__all(ok)) {
            float scale[4];
            #pragma unroll
            for (int r = 0; r < 4; ++r) {
                float nm = fmaxf(mrow[r], mx[r]);
                scale[r] = __expf(mrow[r] - nm);
                mrow[r] = nm;
                lrow[r] *= scale[r];
            }
            #pragma unroll
            for (int cf = 0; cf < 8; ++cf)
                #pragma unroll
                for (int r = 0; r < 4; ++r) oacc[cf][r] *= scale[r];
        }
        // exp + row sums (DPP reduce)
        #pragma unroll
        for (int r = 0; r < 4; ++r) {
            float ps = 0.f;
            #pragma unroll
            for (int nf = 0; nf < 4; ++nf) {
                float pv = __expf(s[nf][r] - mrow[r]); s[nf][r] = pv; ps += pv;
            }
            lrow[r] += red16_add(ps);
        }

        // P -> per-wave LDS (swizzled columns)
        #pragma unroll
        for (int nf = 0; nf < 4; ++nf)
            #pragma unroll
            for (int r = 0; r < 4; ++r)
                Plds[wv][(lg*4+r)*72 + ((nf*16+lc) ^ pxorw)] = (bf16)s[nf][r];

        // O += P @ V
        __builtin_amdgcn_s_setprio(1);
        #pragma unroll
        for (int ks = 0; ks < 2; ++ks) {
            bf16x8 pfr = *(const bf16x8*)&Plds[wv][lc*72 + ((ks*32 + lg*8) ^ pxorr)];
            #pragma unroll
            for (int cf = 0; cf < 8; ++cf) {
                const int vrow = cf*16 + lc;
                bf16x8 vf = *(const bf16x8*)((char*)Vl + vrow*128
                                 + ((ks*64 + lg*16) ^ ((vrow & 7) << 4)));
                oacc[cf] = MFMA16(pfr, vf, oacc[cf]);
            }
        }
        __builtin_amdgcn_s_setprio(0);
        cur ^= 1;
    }

    // store unnormalized partial + m,l
    #pragma unroll
    for (int cf = 0; cf < 8; ++cf)
        #pragma unroll
        for (int r = 0; r < 4; ++r) {
            int q = p0 + wv*16 + lg*4 + r;
            Opart[((size_t)(z*8+b)*3136 + q)*128 + cf*16 + lc] = (bf16)oacc[cf][r];
        }
    if (lc == 0) {
        #pragma unroll
        for (int r = 0; r < 4; ++r) {
            int q = p0 + wv*16 + lg*4 + r;
            size_t idx = (size_t)(z*8+b)*3136 + q;
            mpart[idx] = mrow[r];
            lpart[idx] = lrow[r];
        }
    }
}

// ---------------------------------------------------------------------------
// Kernel C: combine 7 split partials inline, then 1x1 conv (128->256)
// + BN + SiLU + residual (fp32 x). pos-tile 32 (784 blocks), b64-packed
// output transpose.
// ---------------------------------------------------------------------------
__global__ __launch_bounds__(256) void out_kernel(
    const bf16* __restrict__ Opart, const float* __restrict__ mpart,
    const float* __restrict__ lpart, const float* __restrict__ wout,
    const float* __restrict__ gout, const float* __restrict__ bout,
    const float* __restrict__ xg, float* __restrict__ outp)
{
    const int b = blockIdx.x, pt = blockIdx.y;
    const int p0 = pt*32;
    const int t = threadIdx.x;
    const int lane = t & 63, wv = t >> 6;
    const int lc = lane & 15, lg = lane >> 4;

    __shared__ __align__(16) bf16 Olds[32][136];       // [pos][c]
    __shared__ __align__(16) bf16 outlds[4][64][40];   // per-wave [o][pos], b64 packs

    // stage: combine split partials -> normalized O tile in LDS
    {
        const int row = t >> 3;          // 0..31
        const int cc  = (t & 7) * 16;    // c base
        const int q = p0 + row;
        float mz[NSPLIT], wz[NSPLIT];
        float M = -1e30f;
        #pragma unroll
        for (int zz = 0; zz < NSPLIT; ++zz) {
            mz[zz] = mpart[(size_t)(zz*8+b)*3136 + q];
            M = fmaxf(M, mz[zz]);
        }
        float L = 0.f;
        #pragma unroll
        for (int zz = 0; zz < NSPLIT; ++zz) {
            wz[zz] = __expf(mz[zz] - M);
            L += lpart[(size_t)(zz*8+b)*3136 + q] * wz[zz];
        }
        const float inv = 1.f / L;
        #pragma unroll
        for (int zz = 0; zz < NSPLIT; ++zz) wz[zz] *= inv;
        #pragma unroll
        for (int h = 0; h < 2; ++h) {
            const int c8 = cc + h*8;
            float o[8];
            #pragma unroll
            for (int j = 0; j < 8; ++j) o[j] = 0.f;
            #pragma unroll
            for (int zz = 0; zz < NSPLIT; ++zz) {
                bf16x8 v = *(const bf16x8*)(Opart + ((size_t)(zz*8+b)*3136 + q)*128 + c8);
                #pragma unroll
                for (int j = 0; j < 8; ++j) o[j] += wz[zz] * (float)v[j];
            }
            bf16x8 rr;
            #pragma unroll
            for (int j = 0; j < 8; ++j) rr[j] = (bf16)o[j];
            *(bf16x8*)&Olds[row][c8] = rr;
        }
    }
    __syncthreads();

    const f32x4 fz = {0.f,0.f,0.f,0.f};
    f32x4 acc[2][4];
    #pragma unroll
    for (int pf = 0; pf < 2; ++pf)
        #pragma unroll
        for (int nf = 0; nf < 4; ++nf) acc[pf][nf] = fz;

    #pragma unroll
    for (int ks = 0; ks < 4; ++ks) {
        bf16x8 wf[4];
        #pragma unroll
        for (int nf = 0; nf < 4; ++nf)
            wf[nf] = ld8f(wout + (size_t)(wv*64 + nf*16 + lc)*128 + ks*32 + lg*8);
        #pragma unroll
        for (int pf = 0; pf < 2; ++pf) {
            bf16x8 af = *(const bf16x8*)&Olds[pf*16+lc][ks*32+lg*8];
            #pragma unroll
            for (int nf = 0; nf < 4; ++nf)
                acc[pf][nf] = MFMA16(af, wf[nf], acc[pf][nf]);
        }
    }

    // silu -> per-wave transpose buffer, b64 packs (4 consecutive pos)
    #pragma unroll
    for (int nf = 0; nf < 4; ++nf) {
        const int oc = wv*64 + nf*16 + lc;
        const float sc = gout[oc] * BN_SCALE;
        const float bi = bout[oc];
        #pragma unroll
        for (int pf = 0; pf < 2; ++pf) {
            bf16x4 w;
            #pragma unroll
            for (int r = 0; r < 4; ++r)
                w[r] = (bf16)silu_f(acc[pf][nf][r]*sc + bi);
            *(bf16x4*)&outlds[wv][nf*16+lc][pf*16+lg*4] = w;
        }
    }

    // residual add (fp32 x) + coalesced fp32 store: out[b][o][p]
    #pragma unroll
    for (int i = 0; i < 8; ++i) {
        const int orow = i*8 + (lane >> 3);
        const int oc = wv*64 + orow;
        const int p4 = (lane & 7) * 4;
        bf16x4 vo = *(const bf16x4*)&outlds[wv][orow][p4];
        float4 vx = *(const float4*)(xg + ((size_t)b*256 + oc)*3136 + p0 + p4);
        float4 res;
        res.x = (float)vo[0] + vx.x;
        res.y = (float)vo[1] + vx.y;
        res.z = (float)vo[2] + vx.z;
        res.w = (float)vo[3] + vx.w;
        *(float4*)(outp + ((size_t)b*256 + oc)*3136 + p0 + p4) = res;
    }
}

extern "C" void kernel_launch(void* const* d_in, const int* in_sizes, int n_in,
                              void* d_out, int out_size, void* d_ws, size_t ws_size,
                              hipStream_t stream)
{
    const float* x    = (const float*)d_in[0];
    const float* wth  = (const float*)d_in[1];
    const float* gth  = (const float*)d_in[2];
    const float* bth  = (const float*)d_in[3];
    const float* wph  = (const float*)d_in[4];
    const float* gph  = (const float*)d_in[5];
    const float* bph  = (const float*)d_in[6];
    const float* wgg  = (const float*)d_in[7];
    const float* ggg  = (const float*)d_in[8];
    const float* bgg  = (const float*)d_in[9];
    const float* wout = (const float*)d_in[10];
    const float* gout = (const float*)d_in[11];
    const float* bout = (const float*)d_in[12];

    bf16* ws  = (bf16*)d_ws;
    bf16* Qb    = ws;                                  // [8][3136][32]
    bf16* Kb    = Qb + (size_t)8*3136*32;              // [8][3136][32]
    bf16* Vtb   = Kb + (size_t)8*3136*32;              // [8][128][3136]
    bf16* Opart = Vtb + (size_t)8*128*3136;            // [7][8][3136][128]
    float* mpart = (float*)(Opart + (size_t)NSPLIT*8*3136*128);  // [7][8][3136]
    float* lpart = mpart + (size_t)NSPLIT*8*3136;                // [7][8][3136]

    dim3 blk(256);
    qkv_kernel<<<dim3(8,98), blk, 0, stream>>>(x, wth, gth, bth, wph, gph, bph,
                                               wgg, ggg, bgg, Qb, Kb, Vtb);
    attn_kernel<<<dim3(8,49,NSPLIT), blk, 0, stream>>>(Qb, Kb, Vtb, Opart, mpart, lpart);
    out_kernel<<<dim3(8,98), blk, 0, stream>>>(Opart, mpart, lpart,
                                               wout, gout, bout, x, (float*)d_out);
}

// Round 7
// 197.430 us; speedup vs baseline: 1.1235x; 1.0880x over previous
//
#include <hip/hip_runtime.h>

typedef __bf16 bf16;
typedef __bf16 bf16x4 __attribute__((ext_vector_type(4)));
typedef __bf16 bf16x8 __attribute__((ext_vector_type(8)));
typedef float f32x4 __attribute__((ext_vector_type(4)));

#define MFMA16(a,b,c) __builtin_amdgcn_mfma_f32_16x16x32_bf16((a),(b),(c),0,0,0)
#define NSPLIT 7
#define LOG2E 1.4426950408889634f

__device__ __forceinline__ float silu_f(float y){ return y/(1.f+__expf(-y)); }
__device__ __forceinline__ float exp2_f(float x){ return __builtin_amdgcn_exp2f(x); }

// DPP rotate-reduce within 16 lanes (VALU pipe, no LDS ops)
template<int CTRL>
__device__ __forceinline__ float ror_max(float x){
    int y = __builtin_amdgcn_update_dpp(0, __builtin_bit_cast(int,x), CTRL, 0xf, 0xf, false);
    return fmaxf(x, __builtin_bit_cast(float,y));
}
template<int CTRL>
__device__ __forceinline__ float ror_add(float x){
    int y = __builtin_amdgcn_update_dpp(0, __builtin_bit_cast(int,x), CTRL, 0xf, 0xf, false);
    return x + __builtin_bit_cast(float,y);
}
__device__ __forceinline__ float red16_max(float x){
    x = ror_max<0x128>(x); x = ror_max<0x124>(x);
    x = ror_max<0x122>(x); x = ror_max<0x121>(x); return x;
}
__device__ __forceinline__ float red16_add(float x){
    x = ror_add<0x128>(x); x = ror_add<0x124>(x);
    x = ror_add<0x122>(x); x = ror_add<0x121>(x); return x;
}

// load 8 consecutive floats, convert to bf16x8 fragment
__device__ __forceinline__ bf16x8 ld8f(const float* __restrict__ p){
    float4 a = *(const float4*)p;
    float4 b = *(const float4*)(p+4);
    bf16x8 r;
    r[0]=(bf16)a.x; r[1]=(bf16)a.y; r[2]=(bf16)a.z; r[3]=(bf16)a.w;
    r[4]=(bf16)b.x; r[5]=(bf16)b.y; r[6]=(bf16)b.z; r[7]=(bf16)b.w;
    return r;
}

#define BN_SCALE 0.9999950000374997f   // 1/sqrt(1+1e-5)

// ---------------------------------------------------------------------------
// Kernel A: fused 1x1 conv + BN + SiLU for theta(Q), phi(K), g(V).
// 64-pos tile. Staging: pos-coalesced float4 reads (lanes sweep positions),
// in-thread 4x4 transpose, b64 LDS writes.  Q pre-scaled by log2(e).
// Outputs (bf16): Q,K [b][3136][32] pos-major, Vt [b][128][3136] c-major.
// ---------------------------------------------------------------------------
__global__ __launch_bounds__(256) void qkv_kernel(
    const float* __restrict__ xg,
    const float* __restrict__ wth, const float* __restrict__ gth, const float* __restrict__ bth,
    const float* __restrict__ wph, const float* __restrict__ gph, const float* __restrict__ bph,
    const float* __restrict__ wgg, const float* __restrict__ ggg, const float* __restrict__ bgg,
    bf16* __restrict__ Qb, bf16* __restrict__ Kb, bf16* __restrict__ Vtb)
{
    const int b = blockIdx.x, pt = blockIdx.y;
    const int p0 = pt*64;
    const int t = threadIdx.x;
    const int lane = t & 63, wv = t >> 6;
    const int lc = lane & 15, lg = lane >> 4;

    __shared__ __align__(16) bf16 xT[64][264];   // [pos][c], 528B rows

    // stage: lanes (t&15) sweep 64 consecutive positions of one channel
    // (coalesced); thread holds a 4-channel quad, transposes in-register,
    // 16 x b64 LDS writes.
    {
        const int p4 = (t & 15) * 4;     // 0..60
        const int cq = t >> 4;           // 0..15
        #pragma unroll
        for (int r = 0; r < 4; ++r) {
            const int c0 = r*64 + cq*4;
            float4 v0 = *(const float4*)(xg + ((size_t)(b*256 + c0+0))*3136 + p0 + p4);
            float4 v1 = *(const float4*)(xg + ((size_t)(b*256 + c0+1))*3136 + p0 + p4);
            float4 v2 = *(const float4*)(xg + ((size_t)(b*256 + c0+2))*3136 + p0 + p4);
            float4 v3 = *(const float4*)(xg + ((size_t)(b*256 + c0+3))*3136 + p0 + p4);
            bf16x4 w;
            w[0]=(bf16)v0.x; w[1]=(bf16)v1.x; w[2]=(bf16)v2.x; w[3]=(bf16)v3.x;
            *(bf16x4*)&xT[p4+0][c0] = w;
            w[0]=(bf16)v0.y; w[1]=(bf16)v1.y; w[2]=(bf16)v2.y; w[3]=(bf16)v3.y;
            *(bf16x4*)&xT[p4+1][c0] = w;
            w[0]=(bf16)v0.z; w[1]=(bf16)v1.z; w[2]=(bf16)v2.z; w[3]=(bf16)v3.z;
            *(bf16x4*)&xT[p4+2][c0] = w;
            w[0]=(bf16)v0.w; w[1]=(bf16)v1.w; w[2]=(bf16)v2.w; w[3]=(bf16)v3.w;
            *(bf16x4*)&xT[p4+3][c0] = w;
        }
    }
    __syncthreads();

    const f32x4 fz = {0.f,0.f,0.f,0.f};

    for (int tt = 0; tt < 3; ++tt) {
        const int ot = wv*3 + tt;        // 0,1=Q 2,3=K 4..11=V
        if (ot < 4) {
            const float *W, *gam, *bet; bf16* dst; int ol; float post;
            if (ot < 2) { W=wth; gam=gth; bet=bth; dst=Qb; ol=ot*16; post=LOG2E; }
            else        { W=wph; gam=gph; bet=bph; dst=Kb; ol=(ot-2)*16; post=1.f; }
            f32x4 acc[4]; acc[0]=fz; acc[1]=fz; acc[2]=fz; acc[3]=fz;
            #pragma unroll
            for (int ks = 0; ks < 8; ++ks) {
                bf16x8 wf = ld8f(W + (size_t)(ol+lc)*256 + ks*32 + lg*8);
                #pragma unroll
                for (int pf = 0; pf < 4; ++pf) {
                    bf16x8 af = *(const bf16x8*)&xT[pf*16+lc][ks*32+lg*8];
                    acc[pf] = MFMA16(af, wf, acc[pf]);
                }
            }
            const int oc = ol + lc;
            const float sc = gam[oc] * BN_SCALE;
            const float bi = bet[oc];
            #pragma unroll
            for (int pf = 0; pf < 4; ++pf)
                #pragma unroll
                for (int r = 0; r < 4; ++r) {
                    int pos = p0 + pf*16 + lg*4 + r;
                    dst[((size_t)b*3136 + pos)*32 + oc] =
                        (bf16)(silu_f(acc[pf][r]*sc + bi) * post);
                }
        } else {
            const int ol = (ot-4)*16;
            f32x4 acc[4]; acc[0]=fz; acc[1]=fz; acc[2]=fz; acc[3]=fz;
            #pragma unroll
            for (int ks = 0; ks < 8; ++ks) {
                bf16x8 wf = ld8f(wgg + (size_t)(ol+lc)*256 + ks*32 + lg*8);
                #pragma unroll
                for (int pc = 0; pc < 4; ++pc) {
                    bf16x8 xf = *(const bf16x8*)&xT[pc*16+lc][ks*32+lg*8];
                    acc[pc] = MFMA16(wf, xf, acc[pc]);
                }
            }
            #pragma unroll
            for (int r = 0; r < 4; ++r) {
                const int oc = ol + lg*4 + r;
                const float sc = ggg[oc] * BN_SCALE;
                const float bi = bgg[oc];
                #pragma unroll
                for (int pc = 0; pc < 4; ++pc) {
                    int pos = p0 + pc*16 + lc;
                    Vtb[((size_t)b*128 + oc)*3136 + pos] = (bf16)silu_f(acc[pc][r]*sc + bi);
                }
            }
        }
    }
}

// ---------------------------------------------------------------------------
// Kernel B: flash attention, split-K x7, double-buffered K/V (1 barrier/iter),
// DPP softmax reductions, reg-staged prefetch, V swizzle, exp2 domain
// (Q pre-scaled by log2e, m/l tracked in log2 domain).
// ---------------------------------------------------------------------------
__global__ __launch_bounds__(256) void attn_kernel(
    const bf16* __restrict__ Qb, const bf16* __restrict__ Kb,
    const bf16* __restrict__ Vtb, bf16* __restrict__ Opart,
    float* __restrict__ mpart, float* __restrict__ lpart)
{
    const int b = blockIdx.x, qt = blockIdx.y, z = blockIdx.z;
    const int kt0 = z*7, kt1 = kt0+7;
    const int p0 = qt*64;
    const int t = threadIdx.x;
    const int lane = t & 63, wv = t >> 6;
    const int lc = lane & 15, lg = lane >> 4;

    __shared__ __align__(16) bf16 Klds[2][64][40];
    __shared__ __align__(16) bf16 Vlds[2][128*64];   // swizzled, 128B rows
    __shared__ __align__(16) bf16 Plds[4][16*72];

    const bf16* Kbase = Kb + (size_t)b*3136*32;
    const bf16* Vbase = Vtb + (size_t)b*128*3136;

    bf16x8 qf = *(const bf16x8*)(Qb + ((size_t)b*3136 + p0 + wv*16 + lc)*32 + lg*8);

    float mrow[4] = {-1e30f,-1e30f,-1e30f,-1e30f};
    float lrow[4] = {0.f,0.f,0.f,0.f};
    const f32x4 fz = {0.f,0.f,0.f,0.f};
    f32x4 oacc[8];
    #pragma unroll
    for (int cf = 0; cf < 8; ++cf) oacc[cf] = fz;

    const int krow = t >> 2, kkp = (t & 3) * 8;
    const int vrow0 = t >> 3, vj = t & 7;
    const int vxor = (vrow0 & 7) << 4;
    const int pxorw = (lg >> 1) << 4;
    const int pxorr = (lc >> 3) << 4;

    // prologue: prefetch first tile into registers
    bf16x8 kreg, vreg0, vreg1, vreg2, vreg3;
    {
        const int k0 = kt0*64;
        kreg  = *(const bf16x8*)(Kbase + (size_t)(k0+krow)*32 + kkp);
        vreg0 = *(const bf16x8*)(Vbase + (size_t)(0*32+vrow0)*3136 + k0 + vj*8);
        vreg1 = *(const bf16x8*)(Vbase + (size_t)(1*32+vrow0)*3136 + k0 + vj*8);
        vreg2 = *(const bf16x8*)(Vbase + (size_t)(2*32+vrow0)*3136 + k0 + vj*8);
        vreg3 = *(const bf16x8*)(Vbase + (size_t)(3*32+vrow0)*3136 + k0 + vj*8);
    }

    int cur = 0;
    for (int kt = kt0; kt < kt1; ++kt) {
        bf16* Kl = &Klds[cur][0][0];
        bf16* Vl = &Vlds[cur][0];
        *(bf16x8*)&Kl[krow*40 + kkp] = kreg;
        *(bf16x8*)((char*)Vl + (0*32+vrow0)*128 + ((vj*16) ^ vxor)) = vreg0;
        *(bf16x8*)((char*)Vl + (1*32+vrow0)*128 + ((vj*16) ^ vxor)) = vreg1;
        *(bf16x8*)((char*)Vl + (2*32+vrow0)*128 + ((vj*16) ^ vxor)) = vreg2;
        *(bf16x8*)((char*)Vl + (3*32+vrow0)*128 + ((vj*16) ^ vxor)) = vreg3;
        __syncthreads();

        if (kt+1 < kt1) {
            const int kn = (kt+1)*64;
            kreg  = *(const bf16x8*)(Kbase + (size_t)(kn+krow)*32 + kkp);
            vreg0 = *(const bf16x8*)(Vbase + (size_t)(0*32+vrow0)*3136 + kn + vj*8);
            vreg1 = *(const bf16x8*)(Vbase + (size_t)(1*32+vrow0)*3136 + kn + vj*8);
            vreg2 = *(const bf16x8*)(Vbase + (size_t)(2*32+vrow0)*3136 + kn + vj*8);
            vreg3 = *(const bf16x8*)(Vbase + (size_t)(3*32+vrow0)*3136 + kn + vj*8);
        }

        // S tile (log2 domain): D col=key(lc), row=q(lg*4+r)
        f32x4 s[4];
        #pragma unroll
        for (int nf = 0; nf < 4; ++nf) {
            bf16x8 kf = *(const bf16x8*)&Kl[(nf*16+lc)*40 + lg*8];
            s[nf] = MFMA16(qf, kf, fz);
        }

        float mx[4];
        #pragma unroll
        for (int r = 0; r < 4; ++r) {
            float m = fmaxf(fmaxf(s[0][r], s[1][r]), fmaxf(s[2][r], s[3][r]));
            mx[r] = red16_max(m);
        }
        // defer-max: 8 nats = 11.54 in log2 domain
        bool ok = (mx[0] <= mrow[0]+11.5416f) && (mx[1] <= mrow[1]+11.5416f)
               && (mx[2] <= mrow[2]+11.5416f) && (mx[3] <= mrow[3]+11.5416f);
        if (!__all(ok)) {
            float scale[4];
            #pragma unroll
            for (int r = 0; r < 4; ++r) {
                float nm = fmaxf(mrow[r], mx[r]);
                scale[r] = exp2_f(mrow[r] - nm);
                mrow[r] = nm;
                lrow[r] *= scale[r];
            }
            #pragma unroll
            for (int cf = 0; cf < 8; ++cf)
                #pragma unroll
                for (int r = 0; r < 4; ++r) oacc[cf][r] *= scale[r];
        }
        #pragma unroll
        for (int r = 0; r < 4; ++r) {
            float ps = 0.f;
            #pragma unroll
            for (int nf = 0; nf < 4; ++nf) {
                float pv = exp2_f(s[nf][r] - mrow[r]); s[nf][r] = pv; ps += pv;
            }
            lrow[r] += red16_add(ps);
        }

        // P -> per-wave LDS (swizzled columns)
        #pragma unroll
        for (int nf = 0; nf < 4; ++nf)
            #pragma unroll
            for (int r = 0; r < 4; ++r)
                Plds[wv][(lg*4+r)*72 + ((nf*16+lc) ^ pxorw)] = (bf16)s[nf][r];

        // O += P @ V
        __builtin_amdgcn_s_setprio(1);
        #pragma unroll
        for (int ks = 0; ks < 2; ++ks) {
            bf16x8 pfr = *(const bf16x8*)&Plds[wv][lc*72 + ((ks*32 + lg*8) ^ pxorr)];
            #pragma unroll
            for (int cf = 0; cf < 8; ++cf) {
                const int vrow = cf*16 + lc;
                bf16x8 vf = *(const bf16x8*)((char*)Vl + vrow*128
                                 + ((ks*64 + lg*16) ^ ((vrow & 7) << 4)));
                oacc[cf] = MFMA16(pfr, vf, oacc[cf]);
            }
        }
        __builtin_amdgcn_s_setprio(0);
        cur ^= 1;
    }

    #pragma unroll
    for (int cf = 0; cf < 8; ++cf)
        #pragma unroll
        for (int r = 0; r < 4; ++r) {
            int q = p0 + wv*16 + lg*4 + r;
            Opart[((size_t)(z*8+b)*3136 + q)*128 + cf*16 + lc] = (bf16)oacc[cf][r];
        }
    if (lc == 0) {
        #pragma unroll
        for (int r = 0; r < 4; ++r) {
            int q = p0 + wv*16 + lg*4 + r;
            size_t idx = (size_t)(z*8+b)*3136 + q;
            mpart[idx] = mrow[r];
            lpart[idx] = lrow[r];
        }
    }
}

// ---------------------------------------------------------------------------
// Kernel C: combine 7 split partials (log2-domain m), then 1x1 conv
// (128->256) + BN + SiLU + residual (fp32 x). 64-pos tile.
// outlds rows are 72 wide (64 pos + pad) — R6's 40-wide overflow fixed.
// ---------------------------------------------------------------------------
__global__ __launch_bounds__(256) void out_kernel(
    const bf16* __restrict__ Opart, const float* __restrict__ mpart,
    const float* __restrict__ lpart, const float* __restrict__ wout,
    const float* __restrict__ gout, const float* __restrict__ bout,
    const float* __restrict__ xg, float* __restrict__ outp)
{
    const int b = blockIdx.x, pt = blockIdx.y;
    const int p0 = pt*64;
    const int t = threadIdx.x;
    const int lane = t & 63, wv = t >> 6;
    const int lc = lane & 15, lg = lane >> 4;

    __shared__ __align__(16) bf16 Olds[64][136];       // [pos][c]
    __shared__ __align__(16) bf16 outlds[4][64][72];   // per-wave [o][pos(64)+pad]

    // stage: combine split partials -> normalized O tile in LDS
    {
        const int row = t >> 2;          // 0..63
        const int cb = (t & 3) * 32;     // c base
        const int q = p0 + row;
        float mz[NSPLIT], wz[NSPLIT];
        float M = -1e30f;
        #pragma unroll
        for (int zz = 0; zz < NSPLIT; ++zz) {
            mz[zz] = mpart[(size_t)(zz*8+b)*3136 + q];
            M = fmaxf(M, mz[zz]);
        }
        float L = 0.f;
        #pragma unroll
        for (int zz = 0; zz < NSPLIT; ++zz) {
            wz[zz] = exp2_f(mz[zz] - M);
            L += lpart[(size_t)(zz*8+b)*3136 + q] * wz[zz];
        }
        const float inv = 1.f / L;
        #pragma unroll
        for (int zz = 0; zz < NSPLIT; ++zz) wz[zz] *= inv;
        #pragma unroll
        for (int h = 0; h < 4; ++h) {
            const int c8 = cb + h*8;
            float o[8];
            #pragma unroll
            for (int j = 0; j < 8; ++j) o[j] = 0.f;
            #pragma unroll
            for (int zz = 0; zz < NSPLIT; ++zz) {
                bf16x8 v = *(const bf16x8*)(Opart + ((size_t)(zz*8+b)*3136 + q)*128 + c8);
                #pragma unroll
                for (int j = 0; j < 8; ++j) o[j] += wz[zz] * (float)v[j];
            }
            bf16x8 rr;
            #pragma unroll
            for (int j = 0; j < 8; ++j) rr[j] = (bf16)o[j];
            *(bf16x8*)&Olds[row][c8] = rr;
        }
    }
    __syncthreads();

    const f32x4 fz = {0.f,0.f,0.f,0.f};
    f32x4 acc[4][4];
    #pragma unroll
    for (int pf = 0; pf < 4; ++pf)
        #pragma unroll
        for (int nf = 0; nf < 4; ++nf) acc[pf][nf] = fz;

    #pragma unroll
    for (int ks = 0; ks < 4; ++ks) {
        bf16x8 wf[4];
        #pragma unroll
        for (int nf = 0; nf < 4; ++nf)
            wf[nf] = ld8f(wout + (size_t)(wv*64 + nf*16 + lc)*128 + ks*32 + lg*8);
        #pragma unroll
        for (int pf = 0; pf < 4; ++pf) {
            bf16x8 af = *(const bf16x8*)&Olds[pf*16+lc][ks*32+lg*8];
            #pragma unroll
            for (int nf = 0; nf < 4; ++nf)
                acc[pf][nf] = MFMA16(af, wf[nf], acc[pf][nf]);
        }
    }

    // silu -> per-wave transpose buffer, b64 packs (4 consecutive pos)
    #pragma unroll
    for (int nf = 0; nf < 4; ++nf) {
        const int oc = wv*64 + nf*16 + lc;
        const float sc = gout[oc] * BN_SCALE;
        const float bi = bout[oc];
        #pragma unroll
        for (int pf = 0; pf < 4; ++pf) {
            bf16x4 w;
            #pragma unroll
            for (int r = 0; r < 4; ++r)
                w[r] = (bf16)silu_f(acc[pf][nf][r]*sc + bi);
            *(bf16x4*)&outlds[wv][nf*16+lc][pf*16+lg*4] = w;
        }
    }

    // residual add (fp32 x) + coalesced fp32 store: out[b][o][p]
    #pragma unroll
    for (int i = 0; i < 16; ++i) {
        const int orow = i*4 + lg;
        const int oc = wv*64 + orow;
        const int p4 = lc*4;
        bf16x4 vo = *(const bf16x4*)&outlds[wv][orow][p4];
        float4 vx = *(const float4*)(xg + ((size_t)b*256 + oc)*3136 + p0 + p4);
        float4 res;
        res.x = (float)vo[0] + vx.x;
        res.y = (float)vo[1] + vx.y;
        res.z = (float)vo[2] + vx.z;
        res.w = (float)vo[3] + vx.w;
        *(float4*)(outp + ((size_t)b*256 + oc)*3136 + p0 + p4) = res;
    }
}

extern "C" void kernel_launch(void* const* d_in, const int* in_sizes, int n_in,
                              void* d_out, int out_size, void* d_ws, size_t ws_size,
                              hipStream_t stream)
{
    const float* x    = (const float*)d_in[0];
    const float* wth  = (const float*)d_in[1];
    const float* gth  = (const float*)d_in[2];
    const float* bth  = (const float*)d_in[3];
    const float* wph  = (const float*)d_in[4];
    const float* gph  = (const float*)d_in[5];
    const float* bph  = (const float*)d_in[6];
    const float* wgg  = (const float*)d_in[7];
    const float* ggg  = (const float*)d_in[8];
    const float* bgg  = (const float*)d_in[9];
    const float* wout = (const float*)d_in[10];
    const float* gout = (const float*)d_in[11];
    const float* bout = (const float*)d_in[12];

    bf16* ws  = (bf16*)d_ws;
    bf16* Qb    = ws;                                  // [8][3136][32]
    bf16* Kb    = Qb + (size_t)8*3136*32;              // [8][3136][32]
    bf16* Vtb   = Kb + (size_t)8*3136*32;              // [8][128][3136]
    bf16* Opart = Vtb + (size_t)8*128*3136;            // [7][8][3136][128]
    float* mpart = (float*)(Opart + (size_t)NSPLIT*8*3136*128);  // [7][8][3136]
    float* lpart = mpart + (size_t)NSPLIT*8*3136;                // [7][8][3136]

    dim3 blk(256);
    qkv_kernel<<<dim3(8,49), blk, 0, stream>>>(x, wth, gth, bth, wph, gph, bph,
                                               wgg, ggg, bgg, Qb, Kb, Vtb);
    attn_kernel<<<dim3(8,49,NSPLIT), blk, 0, stream>>>(Qb, Kb, Vtb, Opart, mpart, lpart);
    out_kernel<<<dim3(8,49), blk, 0, stream>>>(Opart, mpart, lpart,
                                               wout, gout, bout, x, (float*)d_out);
}